// Round 12
// baseline (166.484 us; speedup 1.0000x reference)
//
#include <hip/hip_runtime.h>
#include <hip/hip_bf16.h>

#define BATCH 4
#define HH 128
#define WW 128
#define CE 32
#define CF 64
#define CIN 96
#define COUT 64

// fused-kernel tile: 4 rows x 16 cols = 64 px
#define WROWS 8
#define WCOLS 20
#define WSTR 104      // padded row stride (bf16): 52 dwords
#define OFFSTR 27     // offm stride (f32): gcd(27,32)=1 -> conflict-free

typedef __bf16 bf16x8 __attribute__((ext_vector_type(8)));
typedef float f32x4 __attribute__((ext_vector_type(4)));
#define MFMA16(a, b, c) __builtin_amdgcn_mfma_f32_16x16x32_bf16(a, b, c, 0, 0, 0)
typedef union { uint4 u; bf16x8 v; } U8;

// ---- workspace byte offsets ----
#define OX_BYTES   (BATCH * HH * WW * CIN * 2)      // 12,582,912  bf16 NHWC
#define WCT_OFFB   OX_BYTES
#define WCT_BYTES  (27 * 32 * 32 * 2)               // 55,296 B
#define WKT_OFFB   (WCT_OFFB + WCT_BYTES)           // wkT2: 27*64*32 bf16 = 110,592 B

// Weight layouts (fragment-coalesced):
//   wcombT2[(tap*3+ks)*32 + oc][r]  r = lg*8+j -> channel c = ks*32 + r
//   wkT2  [(tap*3+ks)*64 + oc][r]

__global__ __launch_bounds__(256) void ln_concat_prep(
    const float* __restrict__ evt, const float* __restrict__ efn,
    const float* __restrict__ w_e, const float* __restrict__ b_e,
    const float* __restrict__ w_f, const float* __restrict__ b_f,
    const float* __restrict__ off_w, const float* __restrict__ mod_w,
    const float* __restrict__ reg_w,
    __hip_bfloat16* __restrict__ ox,
    __hip_bfloat16* __restrict__ wcombT2,
    __hip_bfloat16* __restrict__ wkT2) {
  __shared__ float vals[64 * 97];
  __shared__ float part[4 * 64 * 4];
  __shared__ float stat[64 * 4];

  // ---- weight repack ----
  {
    int e = blockIdx.x * 256 + threadIdx.x;
    const int TOT1 = 27 * 32 * 32;   // 27648
    const int TOT2 = 27 * 64 * 32;   // 55296
    if (e < TOT1) {
      int r = e & 31, g = e >> 5;
      int oc = g & 31, tks = g >> 5;
      int tap = tks / 3, ks = tks % 3, c = ks * 32 + r;
      float v = 0.f;
      if (oc < 18)      v = off_w[(oc * CIN + c) * 9 + tap];
      else if (oc < 27) v = mod_w[((oc - 18) * CIN + c) * 9 + tap];
      wcombT2[e] = __float2bfloat16(v);
    } else if (e < TOT1 + TOT2) {
      int e2 = e - TOT1;
      int r = e2 & 31, g = e2 >> 5;
      int oc = g & 63, tks = g >> 6;
      int tap = tks / 3, ks = tks % 3, c = ks * 32 + r;
      wkT2[e2] = __float2bfloat16(reg_w[(oc * CIN + c) * 9 + tap]);
    }
  }

  int bid = blockIdx.x;
  int wg = (bid & 7) * 128 + (bid >> 3);     // XCD-chunked swizzle (1024 = 8*128)
  int p0 = wg * 64;
  int b = p0 >> 14, y = (p0 >> 7) & 127, x0 = p0 & 127;
  int t = threadIdx.x, px = t & 63, g = t >> 6;

  float sE = 0.f, sE2 = 0.f, sF = 0.f, sF2 = 0.f;
  const float* pe = evt + (((size_t)b * CE) << 14) + (y << 7) + x0 + px;
#pragma unroll
  for (int j = 0; j < 8; ++j) {
    int c = g * 8 + j;
    float v = pe[(size_t)c << 14];
    vals[px * 97 + c] = v; sE += v; sE2 += v * v;
  }
  const float* pf = efn + (((size_t)b * CF) << 14) + (y << 7) + x0 + px;
#pragma unroll
  for (int j = 0; j < 16; ++j) {
    int c = g * 16 + j;
    float v = pf[(size_t)c << 14];
    vals[px * 97 + CE + c] = v; sF += v; sF2 += v * v;
  }
  {
    float4 p4 = {sE, sE2, sF, sF2};
    *(float4*)&part[(g * 64 + px) * 4] = p4;
  }
  __syncthreads();
  if (g == 0) {
    float aE = 0.f, aE2 = 0.f, aF = 0.f, aF2 = 0.f;
#pragma unroll
    for (int gg = 0; gg < 4; ++gg) {
      float4 p4 = *(const float4*)&part[(gg * 64 + px) * 4];
      aE += p4.x; aE2 += p4.y; aF += p4.z; aF2 += p4.w;
    }
    float muE = aE * (1.f / CE);
    float vE = aE2 * (1.f / CE) - muE * muE;
    float muF = aF * (1.f / CF);
    float vF = aF2 * (1.f / CF) - muF * muF;
    float4 s4 = {muE, rsqrtf(vE + 1e-5f), muF, rsqrtf(vF + 1e-5f)};
    *(float4*)&stat[px * 4] = s4;
  }
  __syncthreads();
  uint* orow = (uint*)(ox + (size_t)p0 * CIN);
#pragma unroll
  for (int i = 0; i < 12; ++i) {
    int e = i * 256 + t;
    int xx = e / 48, c = (e % 48) * 2;
    float v0 = vals[xx * 97 + c], v1 = vals[xx * 97 + c + 1];
    float mu, rs, lw0, lb0, lw1, lb1;
    if (c < CE) {
      mu = stat[xx * 4 + 0]; rs = stat[xx * 4 + 1];
      lw0 = w_e[c]; lb0 = b_e[c]; lw1 = w_e[c + 1]; lb1 = b_e[c + 1];
    } else {
      mu = stat[xx * 4 + 2]; rs = stat[xx * 4 + 3];
      lw0 = w_f[c - CE]; lb0 = b_f[c - CE]; lw1 = w_f[c + 1 - CE]; lb1 = b_f[c + 1 - CE];
    }
    float o0 = (v0 - mu) * rs * lw0 + lb0;
    float o1 = (v1 - mu) * rs * lw1 + lb1;
    __hip_bfloat16 h0 = __float2bfloat16(o0), h1 = __float2bfloat16(o1);
    orow[e] = ((uint)*(unsigned short*)&h1 << 16) | (uint)*(unsigned short*)&h0;
  }
}

__device__ __forceinline__ uint blend1(uint u0, uint u1, uint u2, uint u3,
                                       float w0, float w1, float w2, float w3) {
  float lo = w0 * __uint_as_float(u0 << 16) + w1 * __uint_as_float(u1 << 16)
           + w2 * __uint_as_float(u2 << 16) + w3 * __uint_as_float(u3 << 16);
  float hi = w0 * __uint_as_float(u0 & 0xffff0000u) + w1 * __uint_as_float(u1 & 0xffff0000u)
           + w2 * __uint_as_float(u2 & 0xffff0000u) + w3 * __uint_as_float(u3 & 0xffff0000u);
  __hip_bfloat16 bl = __float2bfloat16(lo), bh = __float2bfloat16(hi);
  return ((uint)*(unsigned short*)&bh << 16) | (uint)*(unsigned short*)&bl;
}

// Fused conv(27ch)->deform->bias/leaky/LN. 4x16-px tile, LDS window 8x20,
// 40.2 KB LDS -> 4 blocks/CU. Explicit software pipeline: B-loads issued
// at chunk start, next chunk's corner ds_reads + next tap's params
// prefetched before the blend; blend VALU (~200cy) hides LDS+L2 latency.
__global__ __launch_bounds__(256) void conv_deform_fused(
    const __hip_bfloat16* __restrict__ ox,
    const __hip_bfloat16* __restrict__ wct2,
    const __hip_bfloat16* __restrict__ wkt2,
    const float* __restrict__ off_b, const float* __restrict__ mod_b,
    const float* __restrict__ reg_b,
    const float* __restrict__ lnw, const float* __restrict__ lnb,
    float* __restrict__ out) {
  __shared__ short win[WROWS * WCOLS * WSTR];   // 33,280 B
  __shared__ float offm[64 * OFFSTR];           // 6,912 B
  float* outl = (float*)win;                    // epilogue alias (after barrier)

  int bid = blockIdx.x;
  int wg = (bid & 7) * 128 + (bid >> 3);   // XCD-chunked swizzle (1024 = 8*128)
  int b = wg >> 8;                          // 256 tiles per batch
  int rem = wg & 255;
  int y0 = (rem >> 3) << 2;                 // 32 y-tiles of 4 rows
  int x0 = (rem & 7) << 4;                  // 8 x-tiles of 16 cols
  const __hip_bfloat16* oxb = ox + (((size_t)b) << 14) * CIN;

  int t = threadIdx.x, lane = t & 63, wv = t >> 6;
  int lr = lane & 15, lg = lane >> 4;
  int pxrow = wv;                           // wave owns tile row wv
  int pxcol = lr;

  // ---- stage window (coalesced rows, zero-padded outside image) ----
  for (int u = t; u < WROWS * WCOLS * 12; u += 256) {
    int c8 = u % 12, pos = u / 12;
    int wr = pos / WCOLS, wc = pos % WCOLS;
    int gy = y0 - 2 + wr, gx = x0 - 2 + wc;
    uint4 v = {0u, 0u, 0u, 0u};
    if ((unsigned)gy < 128u && (unsigned)gx < 128u)
      v = *(const uint4*)(oxb + (size_t)((gy << 7) + gx) * CIN + c8 * 8);
    *(uint4*)&win[pos * WSTR + c8 * 8] = v;
  }
  __syncthreads();

  // ---- conv phase: A from window, B global, both 1-chunk prefetched ----
  f32x4 cc0 = {0.f,0.f,0.f,0.f}, cc1 = {0.f,0.f,0.f,0.f};
  {
    U8 cb0[2], cb1[2];
    bf16x8 acur, anxt;
#define CONV_ADDR(CC) ((pxrow + (CC)/3/1 + (CC)/3*0 + ((CC)/3) + 1) * 0)  /* unused */
#define LDA_CONV(CC, DST)                                                   \
    { int tp_ = (CC) / 3, ks_ = (CC) % 3;                                   \
      int wr_ = pxrow + tp_ / 3 + 1, wc_ = pxcol + tp_ % 3 + 1;             \
      (DST) = *(const bf16x8*)&win[(wr_ * WCOLS + wc_) * WSTR + ks_ * 32 + lg * 8]; }
#define LDB_CONV(CC, Q)                                                     \
    { const __hip_bfloat16* wb_ = wct2 + (size_t)(((CC)) * 32) * 32 + lg * 8; \
      cb0[Q].u = *(const uint4*)(wb_ + lr * 32);                            \
      cb1[Q].u = *(const uint4*)(wb_ + (16 + lr) * 32); }
    LDA_CONV(0, acur);
    LDB_CONV(0, 0);
#pragma unroll
    for (int cc = 0; cc < 27; ++cc) {
      const int q = cc & 1;
      if (cc < 26) {
        LDB_CONV(cc + 1, q ^ 1);
        LDA_CONV(cc + 1, anxt);
      }
      cc0 = MFMA16(acur, cb0[q].v, cc0);
      cc1 = MFMA16(acur, cb1[q].v, cc1);
      acur = anxt;
    }
#undef LDA_CONV
#undef LDB_CONV
  }
  // offm epilogue — wave-local
#pragma unroll
  for (int nt = 0; nt < 2; ++nt) {
    int oc = nt * 16 + lr;
    if (oc < 27) {
      float bia = (oc < 18) ? off_b[oc] : mod_b[oc - 18];
      f32x4 a = nt ? cc1 : cc0;
#pragma unroll
      for (int r = 0; r < 4; ++r) {
        float v = a[r] + bia;
        if (oc >= 18) v = 2.f / (1.f + __expf(-v));
        offm[((wv << 4) + (lg << 2) + r) * OFFSTR + oc] = v;
      }
    }
  }

  // ---- deform phase: pipelined ----
  const float* om = offm + ((wv << 4) + lr) * OFFSTR;
  f32x4 ac0 = {0.f,0.f,0.f,0.f}, ac1 = {0.f,0.f,0.f,0.f};
  f32x4 ac2 = {0.f,0.f,0.f,0.f}, ac3 = {0.f,0.f,0.f,0.f};

  int widx[2][4], gidx[2][4];
  float pw[2][4];
  uint4 q[2][4];
  U8 bb0, bb1, bb2, bb3;

#define PARAMS(T, S)                                                          \
  {                                                                           \
    float dyv = om[2 * (T)], dxv = om[2 * (T) + 1], mk = om[18 + (T)];        \
    float psy = (float)(y0 + pxrow + (T) / 3 - 1) + dyv;                      \
    float psx = (float)(x0 + pxcol + (T) % 3 - 1) + dxv;                      \
    float fy = floorf(psy), fx = floorf(psx);                                 \
    float wy1 = psy - fy, wx1 = psx - fx;                                     \
    float wy0 = 1.f - wy1, wx0 = 1.f - wx1;                                   \
    int iy0 = (int)fy, ix0 = (int)fx, iy1 = iy0 + 1, ix1 = ix0 + 1;           \
    float vy0 = ((unsigned)iy0 < 128u) ? 1.f : 0.f;                           \
    float vy1 = ((unsigned)iy1 < 128u) ? 1.f : 0.f;                           \
    float vx0 = ((unsigned)ix0 < 128u) ? 1.f : 0.f;                           \
    float vx1 = ((unsigned)ix1 < 128u) ? 1.f : 0.f;                           \
    int cy0 = min(max(iy0, 0), 127), cy1 = min(max(iy1, 0), 127);             \
    int cx0 = min(max(ix0, 0), 127), cx1 = min(max(ix1, 0), 127);             \
    int ra = cy0 - y0 + 2, rb = cy1 - y0 + 2;                                 \
    int ca = cx0 - x0 + 2, cb = cx1 - x0 + 2;                                 \
    bool ina = (unsigned)ra < (unsigned)WROWS, inb = (unsigned)rb < (unsigned)WROWS; \
    bool inca = (unsigned)ca < (unsigned)WCOLS, incb = (unsigned)cb < (unsigned)WCOLS; \
    widx[S][0] = (ina && inca) ? (ra * WCOLS + ca) * WSTR : -1;               \
    widx[S][1] = (ina && incb) ? (ra * WCOLS + cb) * WSTR : -1;               \
    widx[S][2] = (inb && inca) ? (rb * WCOLS + ca) * WSTR : -1;               \
    widx[S][3] = (inb && incb) ? (rb * WCOLS + cb) * WSTR : -1;               \
    gidx[S][0] = ((cy0 << 7) + cx0) * CIN;                                    \
    gidx[S][1] = ((cy0 << 7) + cx1) * CIN;                                    \
    gidx[S][2] = ((cy1 << 7) + cx0) * CIN;                                    \
    gidx[S][3] = ((cy1 << 7) + cx1) * CIN;                                    \
    pw[S][0] = wy0 * wx0 * vy0 * vx0 * mk;                                    \
    pw[S][1] = wy0 * wx1 * vy0 * vx1 * mk;                                    \
    pw[S][2] = wy1 * wx0 * vy1 * vx0 * mk;                                    \
    pw[S][3] = wy1 * wx1 * vy1 * vx1 * mk;                                    \
  }

#define LOADQ(KS, S, Q)                                                       \
  {                                                                           \
    int koff_ = (KS) * 32 + lg * 8;                                           \
    _Pragma("unroll")                                                         \
    for (int j_ = 0; j_ < 4; ++j_) {                                          \
      int w_ = widx[S][j_];                                                   \
      U8 r_;                                                                  \
      r_.v = *(const bf16x8*)&win[(w_ < 0 ? 0 : w_) + koff_];                 \
      if (w_ < 0) r_.u = *(const uint4*)(oxb + gidx[S][j_] + koff_);          \
      q[Q][j_] = r_.u;                                                        \
    }                                                                         \
  }

#define LOADB(CC)                                                             \
  { const __hip_bfloat16* wb_ = wkt2 + (size_t)((CC) * 64) * 32 + lg * 8;     \
    bb0.u = *(const uint4*)(wb_ + lr * 32);                                   \
    bb1.u = *(const uint4*)(wb_ + (16 + lr) * 32);                            \
    bb2.u = *(const uint4*)(wb_ + (32 + lr) * 32);                            \
    bb3.u = *(const uint4*)(wb_ + (48 + lr) * 32); }

  PARAMS(0, 0);
  LOADQ(0, 0, 0);
#pragma unroll
  for (int cc = 0; cc < 27; ++cc) {
    const int tap = cc / 3, ks = cc % 3;
    const int tp = tap & 1, qp = cc & 1;
    LOADB(cc);                              // global, covered by blend below
    if (ks == 0 && tap < 8) PARAMS(tap + 1, tp ^ 1);
    if (cc < 26) {
      const int ntap = (cc + 1) / 3, nks = (cc + 1) % 3;
      LOADQ(nks, ntap & 1, qp ^ 1);         // next chunk's corners (LDS)
    }
    U8 fa;
    fa.u.x = blend1(q[qp][0].x, q[qp][1].x, q[qp][2].x, q[qp][3].x,
                    pw[tp][0], pw[tp][1], pw[tp][2], pw[tp][3]);
    fa.u.y = blend1(q[qp][0].y, q[qp][1].y, q[qp][2].y, q[qp][3].y,
                    pw[tp][0], pw[tp][1], pw[tp][2], pw[tp][3]);
    fa.u.z = blend1(q[qp][0].z, q[qp][1].z, q[qp][2].z, q[qp][3].z,
                    pw[tp][0], pw[tp][1], pw[tp][2], pw[tp][3]);
    fa.u.w = blend1(q[qp][0].w, q[qp][1].w, q[qp][2].w, q[qp][3].w,
                    pw[tp][0], pw[tp][1], pw[tp][2], pw[tp][3]);
    ac0 = MFMA16(fa.v, bb0.v, ac0);
    ac1 = MFMA16(fa.v, bb1.v, ac1);
    ac2 = MFMA16(fa.v, bb2.v, ac2);
    ac3 = MFMA16(fa.v, bb3.v, ac3);
  }
#undef PARAMS
#undef LOADQ
#undef LOADB
  __syncthreads();   // window reads done; outl may alias win

  // ---- epilogue: bias+leaky -> outl (wave-local), channel-LN, store ----
#pragma unroll
  for (int nt = 0; nt < 4; ++nt) {
    int oc = nt * 16 + lr;
    float bia = reg_b[oc];
    f32x4 a = (nt == 0) ? ac0 : (nt == 1) ? ac1 : (nt == 2) ? ac2 : ac3;
#pragma unroll
    for (int r = 0; r < 4; ++r) {
      float v = a[r] + bia;
      v = (v >= 0.f) ? v : 0.2f * v;
      outl[((wv << 4) + (lg << 2) + r) * 65 + oc] = v;
    }
  }
  {
    int px2 = (wv << 4) + (lane >> 2), part = lane & 3;
    int orow = (px2 >> 4), ocol = px2 & 15;
    float s = 0.f, s2 = 0.f;
#pragma unroll
    for (int j = 0; j < 16; ++j) {
      float v = outl[px2 * 65 + part * 16 + j];
      s += v; s2 += v * v;
    }
    s += __shfl_xor(s, 1); s2 += __shfl_xor(s2, 1);
    s += __shfl_xor(s, 2); s2 += __shfl_xor(s2, 2);
    float mu = s * (1.f / 64.f);
    float var = s2 * (1.f / 64.f) - mu * mu;
    float rs = rsqrtf(var + 1e-5f);
    size_t ob = (size_t)b * COUT * 16384 + (size_t)(y0 + orow) * 128 + x0 + ocol;
#pragma unroll
    for (int j = 0; j < 16; ++j) {
      int oc = part * 16 + j;
      float v = outl[px2 * 65 + oc];
      out[ob + (size_t)oc * 16384] = (v - mu) * rs * lnw[oc] + lnb[oc];
    }
  }
}

extern "C" void kernel_launch(void* const* d_in, const int* in_sizes, int n_in,
                              void* d_out, int out_size, void* d_ws, size_t ws_size,
                              hipStream_t stream) {
  const float* evt      = (const float*)d_in[0];
  const float* efn      = (const float*)d_in[1];
  const float* ln_evt_w = (const float*)d_in[2];
  const float* ln_evt_b = (const float*)d_in[3];
  const float* ln_ef_w  = (const float*)d_in[4];
  const float* ln_ef_b  = (const float*)d_in[5];
  const float* ln_al_w  = (const float*)d_in[6];
  const float* ln_al_b  = (const float*)d_in[7];
  const float* off_w    = (const float*)d_in[8];
  const float* off_b    = (const float*)d_in[9];
  const float* mod_w    = (const float*)d_in[10];
  const float* mod_b    = (const float*)d_in[11];
  const float* reg_w    = (const float*)d_in[12];
  const float* reg_b    = (const float*)d_in[13];
  float* out = (float*)d_out;

  char* wsb = (char*)d_ws;
  __hip_bfloat16* oxb    = (__hip_bfloat16*)wsb;
  __hip_bfloat16* wct2   = (__hip_bfloat16*)(wsb + WCT_OFFB);
  __hip_bfloat16* wkt2   = (__hip_bfloat16*)(wsb + WKT_OFFB);

  ln_concat_prep<<<BATCH * HH * WW / 64, 256, 0, stream>>>(
      evt, efn, ln_evt_w, ln_evt_b, ln_ef_w, ln_ef_b,
      off_w, mod_w, reg_w, oxb, wct2, wkt2);
  conv_deform_fused<<<BATCH * HH * WW / 64, 256, 0, stream>>>(
      oxb, wct2, wkt2, off_b, mod_b, reg_b, ln_al_w, ln_al_b, out);
}